// Round 5
// baseline (6309.441 us; speedup 1.0000x reference)
//
#include <hip/hip_runtime.h>

#define SEQ    59
#define FEAT   64
#define VOCAB  578
#define BATCH  4096
#define UNITS  1024
#define KLSTM  1088   // FEAT + UNITS
#define NPAD   640    // VOCAB padded to 5*128

typedef __bf16 bf16x8 __attribute__((ext_vector_type(8)));
typedef __bf16 bf16x4 __attribute__((ext_vector_type(4)));
typedef float  floatx4 __attribute__((ext_vector_type(4)));

typedef const __attribute__((address_space(1))) char gas_char;
typedef __attribute__((address_space(3))) char las_char;

__device__ __forceinline__ float sigmoid_f(float x) { return 1.f / (1.f + __expf(-x)); }
__device__ __forceinline__ float tanh_f(float x) { float e = __expf(2.f * x); return 1.f - 2.f / (e + 1.f); }

// ---------------- conversion kernels ----------------

__global__ void convert_x_kernel(const float* __restrict__ x, __bf16* __restrict__ xbf) {
    int i = blockIdx.x * 256 + threadIdx.x;
    const int total = BATCH * SEQ * FEAT / 4;
    if (i >= total) return;
    float4 v = ((const float4*)x)[i];
    bf16x4 o;
    o.x = (__bf16)v.x; o.y = (__bf16)v.y; o.z = (__bf16)v.z; o.w = (__bf16)v.w;
    ((bf16x4*)xbf)[i] = o;
}

// Wtp [4096 rows][1088 k] bf16 row-major; row np = ublk*128 + gate*32 + j
__global__ void convert_weights_kernel(const float* __restrict__ kern,
                                       const float* __restrict__ reck,
                                       __bf16* __restrict__ Wtp) {
    int idx = blockIdx.x * 256 + threadIdx.x;
    if (idx >= 4096 * KLSTM) return;
    int np = idx / KLSTM;
    int k  = idx - np * KLSTM;
    int ublk = np >> 7;
    int g    = (np >> 5) & 3;
    int j    = np & 31;
    int n    = g * 1024 + ublk * 32 + j;
    float v = (k < FEAT) ? kern[(size_t)k * 4096 + n]
                         : reck[(size_t)(k - FEAT) * 4096 + n];
    Wtp[idx] = (__bf16)v;
}

__global__ void convert_w2_kernel(const float* __restrict__ w2, __bf16* __restrict__ Wt2p) {
    int idx = blockIdx.x * 256 + threadIdx.x;
    if (idx >= NPAD * 1024) return;
    int n = idx >> 10;
    int k = idx & 1023;
    float v = (n < VOCAB) ? w2[(size_t)k * VOCAB + n] : 0.f;
    Wt2p[idx] = (__bf16)v;
}

// ---------------- LSTM step: 128 batch x 256 gate-cols per block, LDS-FREE ----------------
// MFMA fragments loaded DIRECTLY from global (h / Wtp are row-major with K contiguous):
// per (m,kk) the wave's 64 lanes read 16 rows x one full 64B line -> fully coalesced.
// No __syncthreads, no vmcnt(0) drain -> compiler pipelines loads across kt (AITER-style).
// A frags shared by wn-pair of waves, B frags by wm-pair -> L1 dedup on same CU.
__global__ void __launch_bounds__(256, 2) lstm_step_kernel(
    const __bf16* __restrict__ xbf,
    const __bf16* __restrict__ Wtp,
    const float*  __restrict__ bias,
    const __bf16* __restrict__ hin,
    __bf16*       __restrict__ hout,
    float*        __restrict__ cstate,
    int t)
{
    const int tid  = threadIdx.x;
    const int wid  = tid >> 6;
    const int lane = tid & 63;
    const int ln   = lane & 15;
    const int lk   = lane >> 4;    // 0..3 k-quarter
    const int wm   = wid >> 1;
    const int wn   = wid & 1;
    const int rb   = blockIdx.x;
    const int yb   = blockIdx.y;   // ub-pair: ublk {2*yb, 2*yb+1}

    floatx4 acc[2][4][4];
#pragma unroll
    for (int p = 0; p < 2; ++p)
#pragma unroll
        for (int m = 0; m < 4; ++m)
#pragma unroll
            for (int g = 0; g < 4; ++g)
                acc[p][m][g] = (floatx4){0.f, 0.f, 0.f, 0.f};

    // per-lane base pointers (16B granules)
    const __bf16* aBase[4];   // A row base for each m-frag (h layout; x handled in peel)
#pragma unroll
    for (int m = 0; m < 4; ++m) {
        const int row = rb * 128 + wm * 64 + m * 16 + ln;
        aBase[m] = hin + ((size_t)row << 10);
    }
    const __bf16* bBase[2][4]; // B row base per (p,g)
#pragma unroll
    for (int p = 0; p < 2; ++p)
#pragma unroll
        for (int g = 0; g < 4; ++g) {
            const int n = yb * 256 + p * 128 + g * 32 + wn * 16 + ln;
            bBase[p][g] = Wtp + (size_t)n * KLSTM;
        }

    // ---- kt = 0: A from x (64 k-cols) ----
#pragma unroll
    for (int kk = 0; kk < 2; ++kk) {
        const int kg = kk * 4 + lk;
        bf16x8 a[4], b[2][4];
#pragma unroll
        for (int m = 0; m < 4; ++m) {
            const int row = rb * 128 + wm * 64 + m * 16 + ln;
            a[m] = *(const bf16x8*)(xbf + (size_t)row * (SEQ * FEAT) + t * FEAT + kg * 8);
        }
#pragma unroll
        for (int p = 0; p < 2; ++p)
#pragma unroll
            for (int g = 0; g < 4; ++g)
                b[p][g] = *(const bf16x8*)(bBase[p][g] + kg * 8);
#pragma unroll
        for (int m = 0; m < 4; ++m)
#pragma unroll
            for (int g = 0; g < 4; ++g) {
                acc[0][m][g] = __builtin_amdgcn_mfma_f32_16x16x32_bf16(a[m], b[0][g], acc[0][m][g], 0, 0, 0);
                acc[1][m][g] = __builtin_amdgcn_mfma_f32_16x16x32_bf16(a[m], b[1][g], acc[1][m][g], 0, 0, 0);
            }
    }

    // ---- kt = 1..16: A from h ----
#pragma unroll 2
    for (int kt = 1; kt < 17; ++kt) {
        const int ka = (kt - 1) * 64;  // offset into h row
        const int kb = kt * 64;        // offset into Wtp row
#pragma unroll
        for (int kk = 0; kk < 2; ++kk) {
            const int kg = kk * 4 + lk;
            bf16x8 a[4], b[2][4];
#pragma unroll
            for (int m = 0; m < 4; ++m)
                a[m] = *(const bf16x8*)(aBase[m] + ka + kg * 8);
#pragma unroll
            for (int p = 0; p < 2; ++p)
#pragma unroll
                for (int g = 0; g < 4; ++g)
                    b[p][g] = *(const bf16x8*)(bBase[p][g] + kb + kg * 8);
#pragma unroll
            for (int m = 0; m < 4; ++m)
#pragma unroll
                for (int g = 0; g < 4; ++g) {
                    acc[0][m][g] = __builtin_amdgcn_mfma_f32_16x16x32_bf16(a[m], b[0][g], acc[0][m][g], 0, 0, 0);
                    acc[1][m][g] = __builtin_amdgcn_mfma_f32_16x16x32_bf16(a[m], b[1][g], acc[1][m][g], 0, 0, 0);
                }
        }
    }

    // fused LSTM epilogue: lane owns unit u (per tile p) across all 4 gates
#pragma unroll
    for (int p = 0; p < 2; ++p) {
        const int u  = (yb * 2 + p) * 32 + wn * 16 + ln;
        const float bi  = bias[u];
        const float bfv = bias[UNITS + u];
        const float bg  = bias[2 * UNITS + u];
        const float bo  = bias[3 * UNITS + u];
#pragma unroll
        for (int m = 0; m < 4; ++m) {
            const int row0 = rb * 128 + wm * 64 + m * 16 + lk * 4;
#pragma unroll
            for (int r = 0; r < 4; ++r) {
                const size_t idx = ((size_t)(row0 + r) << 10) + u;
                float ig = sigmoid_f(acc[p][m][0][r] + bi);
                float fg = sigmoid_f(acc[p][m][1][r] + bfv);
                float gg = tanh_f(acc[p][m][2][r] + bg);
                float og = sigmoid_f(acc[p][m][3][r] + bo);
                float cn = fg * cstate[idx] + ig * gg;
                cstate[idx] = cn;
                hout[idx] = (__bf16)(og * tanh_f(cn));
            }
        }
    }
}

// ---------------- final dense: [4096,1024] @ [1024,640] -> logits fp32 ----------------
__global__ void __launch_bounds__(256) dense_kernel(
    const __bf16* __restrict__ hin,
    const __bf16* __restrict__ Wt2p,
    float*        __restrict__ logits)
{
    __shared__ __bf16 As[128 * 64];
    __shared__ __bf16 Bs[128 * 64];

    const int tid  = threadIdx.x;
    const int wid  = tid >> 6;
    const int lane = tid & 63;
    const int ln   = lane & 15;
    const int lk   = lane >> 4;
    const int wm   = wid >> 1;
    const int wn   = wid & 1;
    const int rb   = blockIdx.x;
    const int nb   = blockIdx.y;

    floatx4 acc[4][4];
#pragma unroll
    for (int m = 0; m < 4; ++m)
#pragma unroll
        for (int g = 0; g < 4; ++g)
            acc[m][g] = (floatx4){0.f, 0.f, 0.f, 0.f};

    int s_row[4], s_kgd[4];
#pragma unroll
    for (int q = 0; q < 4; ++q) {
        int flat = q * 256 + tid;
        int row  = flat >> 3;
        s_row[q] = row;
        s_kgd[q] = (flat & 7) ^ (row & 7);
    }

    for (int kt = 0; kt < 16; ++kt) {
        __syncthreads();
#pragma unroll
        for (int q = 0; q < 4; ++q) {
            const int row = s_row[q], kgd = s_kgd[q];
            const __bf16* gp = hin + ((size_t)(rb * 128 + row) << 10) + kt * 64 + kgd * 8;
            __builtin_amdgcn_global_load_lds((gas_char*)gp,
                (las_char*)(As + (size_t)(q * 256 + (wid << 6)) * 8), 16, 0, 0);
        }
#pragma unroll
        for (int q = 0; q < 4; ++q) {
            const int n = s_row[q], kgd = s_kgd[q];
            const __bf16* gp = Wt2p + ((size_t)(nb * 128 + n) << 10) + kt * 64 + kgd * 8;
            __builtin_amdgcn_global_load_lds((gas_char*)gp,
                (las_char*)(Bs + (size_t)(q * 256 + (wid << 6)) * 8), 16, 0, 0);
        }
        __syncthreads();
#pragma unroll
        for (int kk = 0; kk < 2; ++kk) {
            const int kg = kk * 4 + lk;
            bf16x8 a[4], b[4];
#pragma unroll
            for (int m = 0; m < 4; ++m) {
                int row  = wm * 64 + m * 16 + ln;
                int ccol = (kg ^ (row & 7)) * 8;
                a[m] = *(const bf16x8*)(As + row * 64 + ccol);
            }
#pragma unroll
            for (int g = 0; g < 4; ++g) {
                int n    = g * 32 + wn * 16 + ln;
                int ccol = (kg ^ (n & 7)) * 8;
                b[g] = *(const bf16x8*)(Bs + n * 64 + ccol);
            }
#pragma unroll
            for (int m = 0; m < 4; ++m)
#pragma unroll
                for (int g = 0; g < 4; ++g)
                    acc[m][g] = __builtin_amdgcn_mfma_f32_16x16x32_bf16(a[m], b[g], acc[m][g], 0, 0, 0);
        }
    }

#pragma unroll
    for (int m = 0; m < 4; ++m) {
        const int row0 = rb * 128 + wm * 64 + m * 16 + lk * 4;
#pragma unroll
        for (int g = 0; g < 4; ++g) {
            const int n = nb * 128 + g * 32 + wn * 16 + ln;
#pragma unroll
            for (int r = 0; r < 4; ++r)
                logits[(size_t)(row0 + r) * NPAD + n] = acc[m][g][r];
        }
    }
}

// ---------------- row softmax over 578 cols (+b2) ----------------
__global__ void __launch_bounds__(256) softmax_kernel(
    const float* __restrict__ logits,
    const float* __restrict__ b2,
    float* __restrict__ out)
{
    const int row = blockIdx.x;
    const int tid = threadIdx.x;
    __shared__ float red[8];

    float z[3];
    float lmax = -1e30f;
#pragma unroll
    for (int j = 0; j < 3; ++j) {
        int col = tid + j * 256;
        if (col < VOCAB) {
            z[j] = logits[(size_t)row * NPAD + col] + b2[col];
            lmax = fmaxf(lmax, z[j]);
        } else z[j] = -1e30f;
    }
    for (int off = 32; off > 0; off >>= 1) lmax = fmaxf(lmax, __shfl_xor(lmax, off));
    if ((tid & 63) == 0) red[tid >> 6] = lmax;
    __syncthreads();
    lmax = fmaxf(fmaxf(red[0], red[1]), fmaxf(red[2], red[3]));
    __syncthreads();

    float lsum = 0.f;
#pragma unroll
    for (int j = 0; j < 3; ++j) {
        int col = tid + j * 256;
        if (col < VOCAB) { z[j] = __expf(z[j] - lmax); lsum += z[j]; }
    }
    for (int off = 32; off > 0; off >>= 1) lsum += __shfl_xor(lsum, off);
    if ((tid & 63) == 0) red[tid >> 6] = lsum;
    __syncthreads();
    lsum = red[0] + red[1] + red[2] + red[3];
    float inv = 1.f / lsum;
#pragma unroll
    for (int j = 0; j < 3; ++j) {
        int col = tid + j * 256;
        if (col < VOCAB) out[(size_t)row * VOCAB + col] = z[j] * inv;
    }
}

// ---------------- launch ----------------
extern "C" void kernel_launch(void* const* d_in, const int* in_sizes, int n_in,
                              void* d_out, int out_size, void* d_ws, size_t ws_size,
                              hipStream_t stream)
{
    const float* x    = (const float*)d_in[0];
    const float* kern = (const float*)d_in[1];
    const float* reck = (const float*)d_in[2];
    const float* bias = (const float*)d_in[3];
    const float* w2   = (const float*)d_in[4];
    const float* b2   = (const float*)d_in[5];
    float* out = (float*)d_out;

    char* ws = (char*)d_ws;
    size_t off = 0;
    auto alloc = [&](size_t bytes) {
        char* p = ws + off;
        off += (bytes + 255) & ~(size_t)255;
        return p;
    };
    __bf16* Wtp    = (__bf16*)alloc((size_t)4096 * KLSTM * 2);
    __bf16* Wt2p   = (__bf16*)alloc((size_t)NPAD * 1024 * 2);
    __bf16* xbf    = (__bf16*)alloc((size_t)BATCH * SEQ * FEAT * 2);
    __bf16* h0     = (__bf16*)alloc((size_t)BATCH * UNITS * 2);
    __bf16* h1     = (__bf16*)alloc((size_t)BATCH * UNITS * 2);
    float*  cst    = (float*)alloc((size_t)BATCH * UNITS * 4);
    float*  logits = (float*)alloc((size_t)BATCH * NPAD * 4);
    if (off > ws_size) return;  // loud failure: output stays zero

    (void)hipMemsetAsync(h0, 0, (size_t)BATCH * UNITS * 2, stream);
    (void)hipMemsetAsync(cst, 0, (size_t)BATCH * UNITS * 4, stream);

    convert_x_kernel<<<(BATCH * SEQ * FEAT / 4 + 255) / 256, 256, 0, stream>>>(x, xbf);
    convert_weights_kernel<<<(4096 * KLSTM + 255) / 256, 256, 0, stream>>>(kern, reck, Wtp);
    convert_w2_kernel<<<(NPAD * 1024 + 255) / 256, 256, 0, stream>>>(w2, Wt2p);

    __bf16* hin = h0; __bf16* hout = h1;
    for (int t = 0; t < SEQ; ++t) {
        lstm_step_kernel<<<dim3(32, 16), 256, 0, stream>>>(xbf, Wtp, bias, hin, hout, cst, t);
        __bf16* tmp = hin; hin = hout; hout = tmp;
    }

    dense_kernel<<<dim3(32, 5), 256, 0, stream>>>(hin, Wt2p, logits);
    softmax_kernel<<<BATCH, 256, 0, stream>>>(logits, b2, out);
}

// Round 6
// 3588.530 us; speedup vs baseline: 1.7582x; 1.7582x over previous
//
#include <hip/hip_runtime.h>

#define SEQ    59
#define FEAT   64
#define VOCAB  578
#define BATCH  4096
#define UNITS  1024
#define KLSTM  1088   // FEAT + UNITS
#define NPAD   640    // VOCAB padded to 5*128

typedef __bf16 bf16x8 __attribute__((ext_vector_type(8)));
typedef __bf16 bf16x4 __attribute__((ext_vector_type(4)));
typedef float  floatx4 __attribute__((ext_vector_type(4)));

typedef const __attribute__((address_space(1))) char gas_char;
typedef __attribute__((address_space(3))) char las_char;

__device__ __forceinline__ float sigmoid_f(float x) { return 1.f / (1.f + __expf(-x)); }
__device__ __forceinline__ float tanh_f(float x) { float e = __expf(2.f * x); return 1.f - 2.f / (e + 1.f); }

// ---------------- conversion kernels ----------------

__global__ void convert_x_kernel(const float* __restrict__ x, __bf16* __restrict__ xbf) {
    int i = blockIdx.x * 256 + threadIdx.x;
    const int total = BATCH * SEQ * FEAT / 4;
    if (i >= total) return;
    float4 v = ((const float4*)x)[i];
    bf16x4 o;
    o.x = (__bf16)v.x; o.y = (__bf16)v.y; o.z = (__bf16)v.z; o.w = (__bf16)v.w;
    ((bf16x4*)xbf)[i] = o;
}

// Wtp [4096 rows][1088 k] bf16 row-major; row np = ublk*128 + gate*32 + j
__global__ void convert_weights_kernel(const float* __restrict__ kern,
                                       const float* __restrict__ reck,
                                       __bf16* __restrict__ Wtp) {
    int idx = blockIdx.x * 256 + threadIdx.x;
    if (idx >= 4096 * KLSTM) return;
    int np = idx / KLSTM;
    int k  = idx - np * KLSTM;
    int ublk = np >> 7;
    int g    = (np >> 5) & 3;
    int j    = np & 31;
    int n    = g * 1024 + ublk * 32 + j;
    float v = (k < FEAT) ? kern[(size_t)k * 4096 + n]
                         : reck[(size_t)(k - FEAT) * 4096 + n];
    Wtp[idx] = (__bf16)v;
}

__global__ void convert_w2_kernel(const float* __restrict__ w2, __bf16* __restrict__ Wt2p) {
    int idx = blockIdx.x * 256 + threadIdx.x;
    if (idx >= NPAD * 1024) return;
    int n = idx >> 10;
    int k = idx & 1023;
    float v = (n < VOCAB) ? w2[(size_t)k * VOCAB + n] : 0.f;
    Wt2p[idx] = (__bf16)v;
}

// ---------------- persistent fused LSTM sequence kernel ----------------
// 512 blocks = exactly 2/CU (LDS 48KB, <=256 VGPR) -> all co-resident.
// Block (rb,yb) fixed; loops t=0..58. Chains (rb) are independent; within a
// chain, step t+1 waits for all 16 yb-blocks of step t via done[rb][t].
// Coherence: h goes through LLC (agent-scope stores; staging loads aux=SC0|SC1=17),
// flags are agent-scope atomics (execute at LLC); c is block-private (local L2,
// glc load for L1 safety). No L2 flush/invalidate anywhere -> Wtp stays L2-hot.
__global__ void __launch_bounds__(256, 2) lstm_seq_kernel(
    const __bf16* __restrict__ xbf,
    const __bf16* __restrict__ Wtp,
    const float*  __restrict__ bias,
    __bf16* __restrict__ hbuf0,
    __bf16* __restrict__ hbuf1,
    float*  __restrict__ cstate,
    int*    __restrict__ done)   // [32][64]
{
    __shared__ __bf16 As[128 * 64];
    __shared__ __bf16 Bs[2][128 * 64];

    const int tid  = threadIdx.x;
    const int wid  = tid >> 6;
    const int lane = tid & 63;
    const int ln   = lane & 15;
    const int lk   = lane >> 4;
    const int wm   = wid >> 1;
    const int wn   = wid & 1;
    const int bid  = blockIdx.x;
    const int rb   = bid >> 4;    // 32 chains (batch-row groups)
    const int yb   = bid & 15;    // 16 col-blocks per chain

    // XOR-swizzled staging pattern (round-3 proven, 0 conflicts)
    int s_row[4], s_kgd[4];
#pragma unroll
    for (int q = 0; q < 4; ++q) {
        int flat = q * 256 + tid;
        int row  = flat >> 3;
        s_row[q] = row;
        s_kgd[q] = (flat & 7) ^ (row & 7);
    }

    // per-lane epilogue constants
    const int u0 = (yb * 2 + 0) * 32 + wn * 16 + ln;
    const int u1 = (yb * 2 + 1) * 32 + wn * 16 + ln;

#pragma unroll 1
    for (int t = 0; t < SEQ; ++t) {
        const __bf16* hin  = (t & 1) ? hbuf1 : hbuf0;
        __bf16*       hout = (t & 1) ? hbuf0 : hbuf1;

        if (t > 0) {
            if (tid == 0) {
                const int* fp = &done[(rb << 6) + (t - 1)];
                while (__hip_atomic_load(fp, __ATOMIC_RELAXED, __HIP_MEMORY_SCOPE_AGENT) < 16)
                    __builtin_amdgcn_s_sleep(2);
            }
            __syncthreads();
        }

        floatx4 acc[2][4][4];
#pragma unroll
        for (int p = 0; p < 2; ++p)
#pragma unroll
            for (int m = 0; m < 4; ++m)
#pragma unroll
                for (int g = 0; g < 4; ++g)
                    acc[p][m][g] = (floatx4){0.f, 0.f, 0.f, 0.f};

        for (int kt = 0; kt < 17; ++kt) {
            __syncthreads();
            // stage A (128 batch-rows x 64 k)
#pragma unroll
            for (int q = 0; q < 4; ++q) {
                const int row = s_row[q], kgd = s_kgd[q];
                if (kt == 0) {
                    const __bf16* gp = xbf + (size_t)(rb * 128 + row) * (SEQ * FEAT) + t * FEAT + kgd * 8;
                    __builtin_amdgcn_global_load_lds((gas_char*)gp,
                        (las_char*)(As + (size_t)(q * 256 + (wid << 6)) * 8), 16, 0, 0);
                } else {
                    const __bf16* gp = hin + ((size_t)(rb * 128 + row) << 10) + (kt - 1) * 64 + kgd * 8;
                    // aux = SC0|SC1 = 17: device-coherent read from LLC (h crosses XCDs)
                    __builtin_amdgcn_global_load_lds((gas_char*)gp,
                        (las_char*)(As + (size_t)(q * 256 + (wid << 6)) * 8), 16, 0, 17);
                }
            }
            // stage B tiles p=0,1 (L2-cached, read-only)
#pragma unroll
            for (int p = 0; p < 2; ++p) {
#pragma unroll
                for (int q = 0; q < 4; ++q) {
                    const int n = s_row[q], kgd = s_kgd[q];
                    const __bf16* gp = Wtp + (size_t)(yb * 256 + p * 128 + n) * KLSTM + kt * 64 + kgd * 8;
                    __builtin_amdgcn_global_load_lds((gas_char*)gp,
                        (las_char*)(Bs[p] + (size_t)(q * 256 + (wid << 6)) * 8), 16, 0, 0);
                }
            }
            __syncthreads();
            // compute
#pragma unroll
            for (int kk = 0; kk < 2; ++kk) {
                const int kg = kk * 4 + lk;
                bf16x8 a[4], b0[4], b1[4];
#pragma unroll
                for (int m = 0; m < 4; ++m) {
                    int row  = wm * 64 + m * 16 + ln;
                    int ccol = (kg ^ (row & 7)) * 8;
                    a[m] = *(const bf16x8*)(As + row * 64 + ccol);
                }
#pragma unroll
                for (int g = 0; g < 4; ++g) {
                    int n    = g * 32 + wn * 16 + ln;
                    int ccol = (kg ^ (n & 7)) * 8;
                    b0[g] = *(const bf16x8*)(Bs[0] + n * 64 + ccol);
                    b1[g] = *(const bf16x8*)(Bs[1] + n * 64 + ccol);
                }
#pragma unroll
                for (int m = 0; m < 4; ++m)
#pragma unroll
                    for (int g = 0; g < 4; ++g) {
                        acc[0][m][g] = __builtin_amdgcn_mfma_f32_16x16x32_bf16(a[m], b0[g], acc[0][m][g], 0, 0, 0);
                        acc[1][m][g] = __builtin_amdgcn_mfma_f32_16x16x32_bf16(a[m], b1[g], acc[1][m][g], 0, 0, 0);
                    }
            }
        }

        // fused LSTM epilogue
#pragma unroll
        for (int p = 0; p < 2; ++p) {
            const int u = p ? u1 : u0;
            const float bi  = bias[u];
            const float bfv = bias[UNITS + u];
            const float bg  = bias[2 * UNITS + u];
            const float bo  = bias[3 * UNITS + u];
#pragma unroll
            for (int m = 0; m < 4; ++m) {
                const int row0 = rb * 128 + wm * 64 + m * 16 + lk * 4;
#pragma unroll
                for (int r = 0; r < 4; ++r) {
                    const size_t idx = ((size_t)(row0 + r) << 10) + u;
                    float ig = sigmoid_f(acc[p][m][0][r] + bi);
                    float fg = sigmoid_f(acc[p][m][1][r] + bfv);
                    float gg = tanh_f(acc[p][m][2][r] + bg);
                    float og = sigmoid_f(acc[p][m][3][r] + bo);
                    // c is block-private: glc load (L1-safe), plain store (write-through to local L2)
                    float cold = __hip_atomic_load(&cstate[idx], __ATOMIC_RELAXED, __HIP_MEMORY_SCOPE_WORKGROUP);
                    float cn = fg * cold + ig * gg;
                    cstate[idx] = cn;
                    // h crosses XCDs: device-scope store -> LLC coherence point
                    unsigned short hb = __builtin_bit_cast(unsigned short, (__bf16)(og * tanh_f(cn)));
                    __hip_atomic_store((unsigned short*)hout + idx, hb,
                                       __ATOMIC_RELAXED, __HIP_MEMORY_SCOPE_AGENT);
                }
            }
        }

        __syncthreads();  // drains vmcnt: all lanes' h stores ACKed at LLC before flag
        if (tid == 0)
            __hip_atomic_fetch_add(&done[(rb << 6) + t], 1,
                                   __ATOMIC_RELAXED, __HIP_MEMORY_SCOPE_AGENT);
    }
}

// ---------------- final dense: [4096,1024] @ [1024,640] -> logits fp32 ----------------
__global__ void __launch_bounds__(256) dense_kernel(
    const __bf16* __restrict__ hin,
    const __bf16* __restrict__ Wt2p,
    float*        __restrict__ logits)
{
    __shared__ __bf16 As[128 * 64];
    __shared__ __bf16 Bs[128 * 64];

    const int tid  = threadIdx.x;
    const int wid  = tid >> 6;
    const int lane = tid & 63;
    const int ln   = lane & 15;
    const int lk   = lane >> 4;
    const int wm   = wid >> 1;
    const int wn   = wid & 1;
    const int rb   = blockIdx.x;
    const int nb   = blockIdx.y;

    floatx4 acc[4][4];
#pragma unroll
    for (int m = 0; m < 4; ++m)
#pragma unroll
        for (int g = 0; g < 4; ++g)
            acc[m][g] = (floatx4){0.f, 0.f, 0.f, 0.f};

    int s_row[4], s_kgd[4];
#pragma unroll
    for (int q = 0; q < 4; ++q) {
        int flat = q * 256 + tid;
        int row  = flat >> 3;
        s_row[q] = row;
        s_kgd[q] = (flat & 7) ^ (row & 7);
    }

    for (int kt = 0; kt < 16; ++kt) {
        __syncthreads();
#pragma unroll
        for (int q = 0; q < 4; ++q) {
            const int row = s_row[q], kgd = s_kgd[q];
            const __bf16* gp = hin + ((size_t)(rb * 128 + row) << 10) + kt * 64 + kgd * 8;
            __builtin_amdgcn_global_load_lds((gas_char*)gp,
                (las_char*)(As + (size_t)(q * 256 + (wid << 6)) * 8), 16, 0, 0);
        }
#pragma unroll
        for (int q = 0; q < 4; ++q) {
            const int n = s_row[q], kgd = s_kgd[q];
            const __bf16* gp = Wt2p + ((size_t)(nb * 128 + n) << 10) + kt * 64 + kgd * 8;
            __builtin_amdgcn_global_load_lds((gas_char*)gp,
                (las_char*)(Bs + (size_t)(q * 256 + (wid << 6)) * 8), 16, 0, 0);
        }
        __syncthreads();
#pragma unroll
        for (int kk = 0; kk < 2; ++kk) {
            const int kg = kk * 4 + lk;
            bf16x8 a[4], b[4];
#pragma unroll
            for (int m = 0; m < 4; ++m) {
                int row  = wm * 64 + m * 16 + ln;
                int ccol = (kg ^ (row & 7)) * 8;
                a[m] = *(const bf16x8*)(As + row * 64 + ccol);
            }
#pragma unroll
            for (int g = 0; g < 4; ++g) {
                int n    = g * 32 + wn * 16 + ln;
                int ccol = (kg ^ (n & 7)) * 8;
                b[g] = *(const bf16x8*)(Bs + n * 64 + ccol);
            }
#pragma unroll
            for (int m = 0; m < 4; ++m)
#pragma unroll
                for (int g = 0; g < 4; ++g)
                    acc[m][g] = __builtin_amdgcn_mfma_f32_16x16x32_bf16(a[m], b[g], acc[m][g], 0, 0, 0);
        }
    }

#pragma unroll
    for (int m = 0; m < 4; ++m) {
        const int row0 = rb * 128 + wm * 64 + m * 16 + lk * 4;
#pragma unroll
        for (int g = 0; g < 4; ++g) {
            const int n = nb * 128 + g * 32 + wn * 16 + ln;
#pragma unroll
            for (int r = 0; r < 4; ++r)
                logits[(size_t)(row0 + r) * NPAD + n] = acc[m][g][r];
        }
    }
}

// ---------------- row softmax over 578 cols (+b2) ----------------
__global__ void __launch_bounds__(256) softmax_kernel(
    const float* __restrict__ logits,
    const float* __restrict__ b2,
    float* __restrict__ out)
{
    const int row = blockIdx.x;
    const int tid = threadIdx.x;
    __shared__ float red[8];

    float z[3];
    float lmax = -1e30f;
#pragma unroll
    for (int j = 0; j < 3; ++j) {
        int col = tid + j * 256;
        if (col < VOCAB) {
            z[j] = logits[(size_t)row * NPAD + col] + b2[col];
            lmax = fmaxf(lmax, z[j]);
        } else z[j] = -1e30f;
    }
    for (int off = 32; off > 0; off >>= 1) lmax = fmaxf(lmax, __shfl_xor(lmax, off));
    if ((tid & 63) == 0) red[tid >> 6] = lmax;
    __syncthreads();
    lmax = fmaxf(fmaxf(red[0], red[1]), fmaxf(red[2], red[3]));
    __syncthreads();

    float lsum = 0.f;
#pragma unroll
    for (int j = 0; j < 3; ++j) {
        int col = tid + j * 256;
        if (col < VOCAB) { z[j] = __expf(z[j] - lmax); lsum += z[j]; }
    }
    for (int off = 32; off > 0; off >>= 1) lsum += __shfl_xor(lsum, off);
    if ((tid & 63) == 0) red[tid >> 6] = lsum;
    __syncthreads();
    lsum = red[0] + red[1] + red[2] + red[3];
    float inv = 1.f / lsum;
#pragma unroll
    for (int j = 0; j < 3; ++j) {
        int col = tid + j * 256;
        if (col < VOCAB) out[(size_t)row * VOCAB + col] = z[j] * inv;
    }
}

// ---------------- launch ----------------
extern "C" void kernel_launch(void* const* d_in, const int* in_sizes, int n_in,
                              void* d_out, int out_size, void* d_ws, size_t ws_size,
                              hipStream_t stream)
{
    const float* x    = (const float*)d_in[0];
    const float* kern = (const float*)d_in[1];
    const float* reck = (const float*)d_in[2];
    const float* bias = (const float*)d_in[3];
    const float* w2   = (const float*)d_in[4];
    const float* b2   = (const float*)d_in[5];
    float* out = (float*)d_out;

    char* ws = (char*)d_ws;
    size_t off = 0;
    auto alloc = [&](size_t bytes) {
        char* p = ws + off;
        off += (bytes + 255) & ~(size_t)255;
        return p;
    };
    __bf16* Wtp    = (__bf16*)alloc((size_t)4096 * KLSTM * 2);
    __bf16* Wt2p   = (__bf16*)alloc((size_t)NPAD * 1024 * 2);
    __bf16* xbf    = (__bf16*)alloc((size_t)BATCH * SEQ * FEAT * 2);
    __bf16* h0     = (__bf16*)alloc((size_t)BATCH * UNITS * 2);
    __bf16* h1     = (__bf16*)alloc((size_t)BATCH * UNITS * 2);
    float*  cst    = (float*)alloc((size_t)BATCH * UNITS * 4);
    float*  logits = (float*)alloc((size_t)BATCH * NPAD * 4);
    int*    done   = (int*)alloc((size_t)32 * 64 * 4);
    if (off > ws_size) return;  // loud failure: output stays zero

    (void)hipMemsetAsync(h0, 0, (size_t)BATCH * UNITS * 2, stream);
    (void)hipMemsetAsync(cst, 0, (size_t)BATCH * UNITS * 4, stream);
    (void)hipMemsetAsync(done, 0, (size_t)32 * 64 * 4, stream);

    convert_x_kernel<<<(BATCH * SEQ * FEAT / 4 + 255) / 256, 256, 0, stream>>>(x, xbf);
    convert_weights_kernel<<<(4096 * KLSTM + 255) / 256, 256, 0, stream>>>(kern, reck, Wtp);
    convert_w2_kernel<<<(NPAD * 1024 + 255) / 256, 256, 0, stream>>>(w2, Wt2p);

    lstm_seq_kernel<<<512, 256, 0, stream>>>(xbf, Wtp, bias, h0, h1, cst, done);

    // SEQ=59 odd: final h is h1 (step t writes buf[(t+1)&1]; t=58 -> h1)
    dense_kernel<<<dim3(32, 5), 256, 0, stream>>>(h1, Wt2p, logits);
    softmax_kernel<<<BATCH, 256, 0, stream>>>(logits, b2, out);
}

// Round 7
// 3364.749 us; speedup vs baseline: 1.8752x; 1.0665x over previous
//
#include <hip/hip_runtime.h>

#define SEQ    59
#define FEAT   64
#define VOCAB  578
#define BATCH  4096
#define UNITS  1024
#define KLSTM  1088   // FEAT + UNITS
#define NPAD   640    // VOCAB padded to 5*128

#define CWAVES 4
#define PWAVES 4

typedef __bf16 bf16x8 __attribute__((ext_vector_type(8)));
typedef __bf16 bf16x4 __attribute__((ext_vector_type(4)));
typedef float  floatx4 __attribute__((ext_vector_type(4)));

typedef const __attribute__((address_space(1))) char gas_char;
typedef __attribute__((address_space(3))) char las_char;

__device__ __forceinline__ float sigmoid_f(float x) { return 1.f / (1.f + __expf(-x)); }
__device__ __forceinline__ float tanh_f(float x) { float e = __expf(2.f * x); return 1.f - 2.f / (e + 1.f); }

__device__ __forceinline__ void spin_ge(int* f, int target) {
    while (__hip_atomic_load(f, __ATOMIC_ACQUIRE, __HIP_MEMORY_SCOPE_WORKGROUP) < target)
        __builtin_amdgcn_s_sleep(1);
}

// ---------------- conversion kernels ----------------

__global__ void convert_x_kernel(const float* __restrict__ x, __bf16* __restrict__ xbf) {
    int i = blockIdx.x * 256 + threadIdx.x;
    const int total = BATCH * SEQ * FEAT / 4;
    if (i >= total) return;
    float4 v = ((const float4*)x)[i];
    bf16x4 o;
    o.x = (__bf16)v.x; o.y = (__bf16)v.y; o.z = (__bf16)v.z; o.w = (__bf16)v.w;
    ((bf16x4*)xbf)[i] = o;
}

// Wtp [4096 rows][1088 k] bf16 row-major; row np = ublk*128 + gate*32 + j
__global__ void convert_weights_kernel(const float* __restrict__ kern,
                                       const float* __restrict__ reck,
                                       __bf16* __restrict__ Wtp) {
    int idx = blockIdx.x * 256 + threadIdx.x;
    if (idx >= 4096 * KLSTM) return;
    int np = idx / KLSTM;
    int k  = idx - np * KLSTM;
    int ublk = np >> 7;
    int g    = (np >> 5) & 3;
    int j    = np & 31;
    int n    = g * 1024 + ublk * 32 + j;
    float v = (k < FEAT) ? kern[(size_t)k * 4096 + n]
                         : reck[(size_t)(k - FEAT) * 4096 + n];
    Wtp[idx] = (__bf16)v;
}

__global__ void convert_w2_kernel(const float* __restrict__ w2, __bf16* __restrict__ Wt2p) {
    int idx = blockIdx.x * 256 + threadIdx.x;
    if (idx >= NPAD * 1024) return;
    int n = idx >> 10;
    int k = idx & 1023;
    float v = (n < VOCAB) ? w2[(size_t)k * VOCAB + n] : 0.f;
    Wt2p[idx] = (__bf16)v;
}

// ---------------- LSTM step: producer-consumer wave-specialized ----------------
// 512 thr = 8 waves. Waves 0-3 (consumers): round-3 identical 128x256 MFMA tile.
// Waves 4-7 (producers): global_load_lds into double-buffered LDS (96 KB dyn).
// Per-wave vmcnt: producer drains never stall consumers -> AITER-style overlap
// without cross-block sync (deadlock-free: all 8 waves co-resident per block).
// Handshake: monotonic LDS counters rdy[2]/dn[2], acquire/release.
// Block (rb, Yp) does sub-tiles Y = 2*Yp + {0,1} sequentially: 34 phases;
// phase buffer = phase&1, use-round r = phase>>1. Sub-1 staging overlaps
// sub-0 epilogue (hides c/h HBM traffic). Grid 256 = 1 block/CU, Yp-major
// (bid&7 = Yp): each XCD sees one 512-col Wtp slab (1.1 MB, L2-resident).
__global__ void __launch_bounds__(512, 2) lstm_step_kernel(
    const __bf16* __restrict__ xbf,
    const __bf16* __restrict__ Wtp,
    const float*  __restrict__ bias,
    const __bf16* __restrict__ hin,
    __bf16*       __restrict__ hout,
    float*        __restrict__ cstate,
    int t)
{
    extern __shared__ __bf16 smem[];       // As[2][8192] then Bs[2][2][8192]
    __bf16* As = smem;                     // 2 x 16 KB
    __bf16* Bs = smem + 2 * 8192;          // 2 x 2 x 16 KB
    __shared__ int rdy[2];
    __shared__ int dn[2];

    const int tid  = threadIdx.x;
    const int wid  = tid >> 6;
    const int lane = tid & 63;
    const int bid  = blockIdx.x;
    const int Yp   = bid & 7;
    const int rb   = bid >> 3;

    if (tid < 2) { rdy[tid] = 0; dn[tid] = 0; }
    __syncthreads();   // the only block-wide barrier

    if (wid >= CWAVES) {
        // ================= PRODUCER =================
        const int ptid = tid - CWAVES * 64;
        const int pwid = wid - CWAVES;
        int s_row[4], s_kgd[4];
#pragma unroll
        for (int q = 0; q < 4; ++q) {
            int flat = q * 256 + ptid;
            int row  = flat >> 3;
            s_row[q] = row;
            s_kgd[q] = (flat & 7) ^ (row & 7);
        }
#pragma unroll 1
        for (int phase = 0; phase < 34; ++phase) {
            const int b   = phase & 1;
            const int r   = phase >> 1;
            const int sub = (phase >= 17) ? 1 : 0;
            const int kt  = phase - sub * 17;
            const int Y   = Yp * 2 + sub;
            if (phase >= 2) spin_ge(&dn[b], CWAVES * r);
            __bf16* Ad = As + b * 8192;
            __bf16* Bd = Bs + b * 2 * 8192;
            // A: 4 chunks/thread
#pragma unroll
            for (int q = 0; q < 4; ++q) {
                const int row = s_row[q], kgd = s_kgd[q];
                const __bf16* gp;
                if (kt == 0)
                    gp = xbf + (size_t)(rb * 128 + row) * (SEQ * FEAT) + t * FEAT + kgd * 8;
                else
                    gp = hin + ((size_t)(rb * 128 + row) << 10) + (kt - 1) * 64 + kgd * 8;
                __builtin_amdgcn_global_load_lds((gas_char*)gp,
                    (las_char*)(Ad + (size_t)(q * 256 + (pwid << 6)) * 8), 16, 0, 0);
            }
            // B: 2 p-tiles x 4 chunks/thread
#pragma unroll
            for (int p = 0; p < 2; ++p) {
#pragma unroll
                for (int q = 0; q < 4; ++q) {
                    const int n = s_row[q], kgd = s_kgd[q];
                    const __bf16* gp = Wtp + (size_t)(Y * 256 + p * 128 + n) * KLSTM + kt * 64 + kgd * 8;
                    __builtin_amdgcn_global_load_lds((gas_char*)gp,
                        (las_char*)(Bd + p * 8192 + (size_t)(q * 256 + (pwid << 6)) * 8), 16, 0, 0);
                }
            }
            __builtin_amdgcn_s_waitcnt(0x0F70);   // vmcnt(0): LDS writes landed
            if (lane == 0)
                __hip_atomic_fetch_add(&rdy[b], 1, __ATOMIC_RELEASE, __HIP_MEMORY_SCOPE_WORKGROUP);
        }
    } else {
        // ================= CONSUMER (round-3 math, bit-identical) =================
        const int ln = lane & 15;
        const int lk = lane >> 4;
        const int wm = wid >> 1;
        const int wn = wid & 1;

#pragma unroll 1
        for (int sub = 0; sub < 2; ++sub) {
            const int Y = Yp * 2 + sub;
            floatx4 acc[2][4][4];
#pragma unroll
            for (int p = 0; p < 2; ++p)
#pragma unroll
                for (int m = 0; m < 4; ++m)
#pragma unroll
                    for (int g = 0; g < 4; ++g)
                        acc[p][m][g] = (floatx4){0.f, 0.f, 0.f, 0.f};

#pragma unroll 1
            for (int kt = 0; kt < 17; ++kt) {
                const int phase = sub * 17 + kt;
                const int b = phase & 1;
                const int r = phase >> 1;
                spin_ge(&rdy[b], PWAVES * (r + 1));
                const __bf16* Ab  = As + b * 8192;
                const __bf16* Bb0 = Bs + b * 2 * 8192;
                const __bf16* Bb1 = Bb0 + 8192;
#pragma unroll
                for (int kk = 0; kk < 2; ++kk) {
                    const int kg = kk * 4 + lk;
                    bf16x8 a[4], b0[4], b1[4];
#pragma unroll
                    for (int m = 0; m < 4; ++m) {
                        int row  = wm * 64 + m * 16 + ln;
                        int ccol = (kg ^ (row & 7)) * 8;
                        a[m] = *(const bf16x8*)(Ab + row * 64 + ccol);
                    }
#pragma unroll
                    for (int g = 0; g < 4; ++g) {
                        int n    = g * 32 + wn * 16 + ln;
                        int ccol = (kg ^ (n & 7)) * 8;
                        b0[g] = *(const bf16x8*)(Bb0 + n * 64 + ccol);
                        b1[g] = *(const bf16x8*)(Bb1 + n * 64 + ccol);
                    }
#pragma unroll
                    for (int m = 0; m < 4; ++m)
#pragma unroll
                        for (int g = 0; g < 4; ++g) {
                            acc[0][m][g] = __builtin_amdgcn_mfma_f32_16x16x32_bf16(a[m], b0[g], acc[0][m][g], 0, 0, 0);
                            acc[1][m][g] = __builtin_amdgcn_mfma_f32_16x16x32_bf16(a[m], b1[g], acc[1][m][g], 0, 0, 0);
                        }
                }
                if (lane == 0)
                    __hip_atomic_fetch_add(&dn[b], 1, __ATOMIC_RELEASE, __HIP_MEMORY_SCOPE_WORKGROUP);
            }

            // fused LSTM epilogue for this sub-tile
#pragma unroll
            for (int p = 0; p < 2; ++p) {
                const int u  = (Y * 2 + p) * 32 + wn * 16 + ln;
                const float bi  = bias[u];
                const float bfv = bias[UNITS + u];
                const float bg  = bias[2 * UNITS + u];
                const float bo  = bias[3 * UNITS + u];
#pragma unroll
                for (int m = 0; m < 4; ++m) {
                    const int row0 = rb * 128 + wm * 64 + m * 16 + lk * 4;
#pragma unroll
                    for (int rr = 0; rr < 4; ++rr) {
                        const size_t idx = ((size_t)(row0 + rr) << 10) + u;
                        float ig = sigmoid_f(acc[p][m][0][rr] + bi);
                        float fg = sigmoid_f(acc[p][m][1][rr] + bfv);
                        float gg = tanh_f(acc[p][m][2][rr] + bg);
                        float og = sigmoid_f(acc[p][m][3][rr] + bo);
                        float cn = fg * cstate[idx] + ig * gg;
                        cstate[idx] = cn;
                        hout[idx] = (__bf16)(og * tanh_f(cn));
                    }
                }
            }
        }
    }
}

// ---------------- final dense: [4096,1024] @ [1024,640] -> logits fp32 ----------------
__global__ void __launch_bounds__(256) dense_kernel(
    const __bf16* __restrict__ hin,
    const __bf16* __restrict__ Wt2p,
    float*        __restrict__ logits)
{
    __shared__ __bf16 As[128 * 64];
    __shared__ __bf16 Bs[128 * 64];

    const int tid  = threadIdx.x;
    const int wid  = tid >> 6;
    const int lane = tid & 63;
    const int ln   = lane & 15;
    const int lk   = lane >> 4;
    const int wm   = wid >> 1;
    const int wn   = wid & 1;
    const int rb   = blockIdx.x;
    const int nb   = blockIdx.y;

    floatx4 acc[4][4];
#pragma unroll
    for (int m = 0; m < 4; ++m)
#pragma unroll
        for (int g = 0; g < 4; ++g)
            acc[m][g] = (floatx4){0.f, 0.f, 0.f, 0.f};

    int s_row[4], s_kgd[4];
#pragma unroll
    for (int q = 0; q < 4; ++q) {
        int flat = q * 256 + tid;
        int row  = flat >> 3;
        s_row[q] = row;
        s_kgd[q] = (flat & 7) ^ (row & 7);
    }

    for (int kt = 0; kt < 16; ++kt) {
        __syncthreads();
#pragma unroll
        for (int q = 0; q < 4; ++q) {
            const int row = s_row[q], kgd = s_kgd[q];
            const __bf16* gp = hin + ((size_t)(rb * 128 + row) << 10) + kt * 64 + kgd * 8;
            __builtin_amdgcn_global_load_lds((gas_char*)gp,
                (las_char*)(As + (size_t)(q * 256 + (wid << 6)) * 8), 16, 0, 0);
        }
#pragma unroll
        for (int q = 0; q < 4; ++q) {
            const int n = s_row[q], kgd = s_kgd[q];
            const __bf16* gp = Wt2p + ((size_t)(nb * 128 + n) << 10) + kt * 64 + kgd * 8;
            __builtin_amdgcn_global_load_lds((gas_char*)gp,
                (las_char*)(Bs + (size_t)(q * 256 + (wid << 6)) * 8), 16, 0, 0);
        }
        __syncthreads();
#pragma unroll
        for (int kk = 0; kk < 2; ++kk) {
            const int kg = kk * 4 + lk;
            bf16x8 a[4], b[4];
#pragma unroll
            for (int m = 0; m < 4; ++m) {
                int row  = wm * 64 + m * 16 + ln;
                int ccol = (kg ^ (row & 7)) * 8;
                a[m] = *(const bf16x8*)(As + row * 64 + ccol);
            }
#pragma unroll
            for (int g = 0; g < 4; ++g) {
                int n    = g * 32 + wn * 16 + ln;
                int ccol = (kg ^ (n & 7)) * 8;
                b[g] = *(const bf16x8*)(Bs + n * 64 + ccol);
            }
#pragma unroll
            for (int m = 0; m < 4; ++m)
#pragma unroll
                for (int g = 0; g < 4; ++g)
                    acc[m][g] = __builtin_amdgcn_mfma_f32_16x16x32_bf16(a[m], b[g], acc[m][g], 0, 0, 0);
        }
    }

#pragma unroll
    for (int m = 0; m < 4; ++m) {
        const int row0 = rb * 128 + wm * 64 + m * 16 + lk * 4;
#pragma unroll
        for (int g = 0; g < 4; ++g) {
            const int n = nb * 128 + g * 32 + wn * 16 + ln;
#pragma unroll
            for (int r = 0; r < 4; ++r)
                logits[(size_t)(row0 + r) * NPAD + n] = acc[m][g][r];
        }
    }
}

// ---------------- row softmax over 578 cols (+b2) ----------------
__global__ void __launch_bounds__(256) softmax_kernel(
    const float* __restrict__ logits,
    const float* __restrict__ b2,
    float* __restrict__ out)
{
    const int row = blockIdx.x;
    const int tid = threadIdx.x;
    __shared__ float red[8];

    float z[3];
    float lmax = -1e30f;
#pragma unroll
    for (int j = 0; j < 3; ++j) {
        int col = tid + j * 256;
        if (col < VOCAB) {
            z[j] = logits[(size_t)row * NPAD + col] + b2[col];
            lmax = fmaxf(lmax, z[j]);
        } else z[j] = -1e30f;
    }
    for (int off = 32; off > 0; off >>= 1) lmax = fmaxf(lmax, __shfl_xor(lmax, off));
    if ((tid & 63) == 0) red[tid >> 6] = lmax;
    __syncthreads();
    lmax = fmaxf(fmaxf(red[0], red[1]), fmaxf(red[2], red[3]));
    __syncthreads();

    float lsum = 0.f;
#pragma unroll
    for (int j = 0; j < 3; ++j) {
        int col = tid + j * 256;
        if (col < VOCAB) { z[j] = __expf(z[j] - lmax); lsum += z[j]; }
    }
    for (int off = 32; off > 0; off >>= 1) lsum += __shfl_xor(lsum, off);
    if ((tid & 63) == 0) red[tid >> 6] = lsum;
    __syncthreads();
    lsum = red[0] + red[1] + red[2] + red[3];
    float inv = 1.f / lsum;
#pragma unroll
    for (int j = 0; j < 3; ++j) {
        int col = tid + j * 256;
        if (col < VOCAB) out[(size_t)row * VOCAB + col] = z[j] * inv;
    }
}

// ---------------- launch ----------------
extern "C" void kernel_launch(void* const* d_in, const int* in_sizes, int n_in,
                              void* d_out, int out_size, void* d_ws, size_t ws_size,
                              hipStream_t stream)
{
    const float* x    = (const float*)d_in[0];
    const float* kern = (const float*)d_in[1];
    const float* reck = (const float*)d_in[2];
    const float* bias = (const float*)d_in[3];
    const float* w2   = (const float*)d_in[4];
    const float* b2   = (const float*)d_in[5];
    float* out = (float*)d_out;

    char* ws = (char*)d_ws;
    size_t off = 0;
    auto alloc = [&](size_t bytes) {
        char* p = ws + off;
        off += (bytes + 255) & ~(size_t)255;
        return p;
    };
    __bf16* Wtp    = (__bf16*)alloc((size_t)4096 * KLSTM * 2);
    __bf16* Wt2p   = (__bf16*)alloc((size_t)NPAD * 1024 * 2);
    __bf16* xbf    = (__bf16*)alloc((size_t)BATCH * SEQ * FEAT * 2);
    __bf16* h0     = (__bf16*)alloc((size_t)BATCH * UNITS * 2);
    __bf16* h1     = (__bf16*)alloc((size_t)BATCH * UNITS * 2);
    float*  cst    = (float*)alloc((size_t)BATCH * UNITS * 4);
    float*  logits = (float*)alloc((size_t)BATCH * NPAD * 4);
    if (off > ws_size) return;  // loud failure: output stays zero

    // allow 96 KB dynamic LDS (idempotent; not a stream op -> graph-capture safe)
    (void)hipFuncSetAttribute((const void*)lstm_step_kernel,
                              hipFuncAttributeMaxDynamicSharedMemorySize, 96 * 1024);

    (void)hipMemsetAsync(h0, 0, (size_t)BATCH * UNITS * 2, stream);
    (void)hipMemsetAsync(cst, 0, (size_t)BATCH * UNITS * 4, stream);

    convert_x_kernel<<<(BATCH * SEQ * FEAT / 4 + 255) / 256, 256, 0, stream>>>(x, xbf);
    convert_weights_kernel<<<(4096 * KLSTM + 255) / 256, 256, 0, stream>>>(kern, reck, Wtp);
    convert_w2_kernel<<<(NPAD * 1024 + 255) / 256, 256, 0, stream>>>(w2, Wt2p);

    __bf16* hin = h0; __bf16* hout = h1;
    for (int t = 0; t < SEQ; ++t) {
        lstm_step_kernel<<<256, 512, 96 * 1024, stream>>>(xbf, Wtp, bias, hin, hout, cst, t);
        __bf16* tmp = hin; hin = hout; hout = tmp;
    }

    dense_kernel<<<dim3(32, 5), 256, 0, stream>>>(hin, Wt2p, logits);
    softmax_kernel<<<BATCH, 256, 0, stream>>>(logits, b2, out);
}

// Round 8
// 2690.493 us; speedup vs baseline: 2.3451x; 1.2506x over previous
//
#include <hip/hip_runtime.h>

#define SEQ    59
#define FEAT   64
#define VOCAB  578
#define BATCH  4096
#define UNITS  1024
#define KLSTM  1088   // FEAT + UNITS
#define NPAD   640    // VOCAB padded to 5*128

typedef __bf16 bf16x8 __attribute__((ext_vector_type(8)));
typedef __bf16 bf16x4 __attribute__((ext_vector_type(4)));
typedef float  floatx4 __attribute__((ext_vector_type(4)));

typedef const __attribute__((address_space(1))) char gas_char;
typedef __attribute__((address_space(3))) char las_char;

__device__ __forceinline__ float sigmoid_f(float x) { return 1.f / (1.f + __expf(-x)); }
__device__ __forceinline__ float tanh_f(float x) { float e = __expf(2.f * x); return 1.f - 2.f / (e + 1.f); }

// ---------------- conversion kernels ----------------

__global__ void convert_x_kernel(const float* __restrict__ x, __bf16* __restrict__ xbf) {
    int i = blockIdx.x * 256 + threadIdx.x;
    const int total = BATCH * SEQ * FEAT / 4;
    if (i >= total) return;
    float4 v = ((const float4*)x)[i];
    bf16x4 o;
    o.x = (__bf16)v.x; o.y = (__bf16)v.y; o.z = (__bf16)v.z; o.w = (__bf16)v.w;
    ((bf16x4*)xbf)[i] = o;
}

// Wtp [4096 rows][1088 k] bf16 row-major; row np = ublk*128 + gate*32 + j
__global__ void convert_weights_kernel(const float* __restrict__ kern,
                                       const float* __restrict__ reck,
                                       __bf16* __restrict__ Wtp) {
    int idx = blockIdx.x * 256 + threadIdx.x;
    if (idx >= 4096 * KLSTM) return;
    int np = idx / KLSTM;
    int k  = idx - np * KLSTM;
    int ublk = np >> 7;
    int g    = (np >> 5) & 3;
    int j    = np & 31;
    int n    = g * 1024 + ublk * 32 + j;
    float v = (k < FEAT) ? kern[(size_t)k * 4096 + n]
                         : reck[(size_t)(k - FEAT) * 4096 + n];
    Wtp[idx] = (__bf16)v;
}

__global__ void convert_w2_kernel(const float* __restrict__ w2, __bf16* __restrict__ Wt2p) {
    int idx = blockIdx.x * 256 + threadIdx.x;
    if (idx >= NPAD * 1024) return;
    int n = idx >> 10;
    int k = idx & 1023;
    float v = (n < VOCAB) ? w2[(size_t)k * VOCAB + n] : 0.f;
    Wt2p[idx] = (__bf16)v;
}

// ---------------- LSTM step: 256 batch x 256 gate-cols per block ----------------
// 512 thr = 8 waves (4 wm x 2 wn), ALL issuing MFMA (full TLP, round-7 lesson).
// Wave tile = 64 rows x 128 cols (round-3 proven: acc 128 VGPR, 12 ds_read : 32 MFMA).
// Double-buffered LDS (A 2x32KB + B 2x32KB = 128 KB) -> 1 block/CU, grid 256 exact.
// ONE barrier per kt: iter kt = { barrier; issue stage(kt+1); compute(kt) }.
// The vmcnt(0) drain before the NEXT barrier happens after a full compute phase,
// so staging latency is hidden (the m97 2-barrier drain is eliminated).
__global__ void __launch_bounds__(512, 2) lstm_step_kernel(
    const __bf16* __restrict__ xbf,
    const __bf16* __restrict__ Wtp,
    const float*  __restrict__ bias,
    const __bf16* __restrict__ hin,
    __bf16*       __restrict__ hout,
    float*        __restrict__ cstate,
    int t)
{
    extern __shared__ __bf16 smem[];
    __bf16* As = smem;            // 2 x 16384 elems (32 KB each buffer)
    __bf16* Bs = smem + 32768;    // 2 x 16384 elems

    const int tid  = threadIdx.x;   // 0..511
    const int wid  = tid >> 6;      // 0..7
    const int lane = tid & 63;
    const int ln   = lane & 15;
    const int lk   = lane >> 4;
    const int wm   = wid >> 1;      // 0..3 (64-row slab)
    const int wn   = wid & 1;       // 0..1 (128-col slab = ublk)
    const int bid  = blockIdx.x;
    const int yb   = bid & 15;      // bid%8 tracks yb -> XCD shares Wtp slab
    const int rb   = bid >> 4;

    // staging pattern: 4 chunks/thread for A, 4 for B (2048 chunks of 16B each)
    int s_row[4], s_kgd[4];
#pragma unroll
    for (int q = 0; q < 4; ++q) {
        int flat = q * 512 + tid;
        int row  = flat >> 3;
        s_row[q] = row;
        s_kgd[q] = (flat & 7) ^ (row & 7);
    }

    floatx4 acc[4][4][2];   // [m][gate][h]
#pragma unroll
    for (int m = 0; m < 4; ++m)
#pragma unroll
        for (int g = 0; g < 4; ++g)
#pragma unroll
            for (int h = 0; h < 2; ++h)
                acc[m][g][h] = (floatx4){0.f, 0.f, 0.f, 0.f};

    // ---- prologue: stage kt=0 into buffer 0 (A from x, B k=0..63) ----
#pragma unroll
    for (int q = 0; q < 4; ++q) {
        const int row = s_row[q], kgd = s_kgd[q];
        const __bf16* gp = xbf + (size_t)(rb * 256 + row) * (SEQ * FEAT) + t * FEAT + kgd * 8;
        __builtin_amdgcn_global_load_lds((gas_char*)gp,
            (las_char*)(As + (size_t)(q * 512 + (wid << 6)) * 8), 16, 0, 0);
    }
#pragma unroll
    for (int q = 0; q < 4; ++q) {
        const int n = s_row[q], kgd = s_kgd[q];
        const __bf16* gp = Wtp + (size_t)(yb * 256 + n) * KLSTM + kgd * 8;
        __builtin_amdgcn_global_load_lds((gas_char*)gp,
            (las_char*)(Bs + (size_t)(q * 512 + (wid << 6)) * 8), 16, 0, 0);
    }

    // ---- main loop: kt = 0..15 (stage kt+1, compute kt); kt=16 peeled ----
#pragma unroll 1
    for (int kt = 0; kt < 16; ++kt) {
        const int cb = kt & 1;          // compute buffer
        const int sb = cb ^ 1;          // stage buffer
        __syncthreads();                // compute(kt-1) done + stage(kt) landed

        // issue stage(kt+1): A from h k-range kt*64, B k-range (kt+1)*64
#pragma unroll
        for (int q = 0; q < 4; ++q) {
            const int row = s_row[q], kgd = s_kgd[q];
            const __bf16* gp = hin + ((size_t)(rb * 256 + row) << 10) + kt * 64 + kgd * 8;
            __builtin_amdgcn_global_load_lds((gas_char*)gp,
                (las_char*)(As + sb * 16384 + (size_t)(q * 512 + (wid << 6)) * 8), 16, 0, 0);
        }
#pragma unroll
        for (int q = 0; q < 4; ++q) {
            const int n = s_row[q], kgd = s_kgd[q];
            const __bf16* gp = Wtp + (size_t)(yb * 256 + n) * KLSTM + (kt + 1) * 64 + kgd * 8;
            __builtin_amdgcn_global_load_lds((gas_char*)gp,
                (las_char*)(Bs + sb * 16384 + (size_t)(q * 512 + (wid << 6)) * 8), 16, 0, 0);
        }

        // compute(kt) from buffer cb
        const __bf16* Ab = As + cb * 16384;
        const __bf16* Bb = Bs + cb * 16384;
#pragma unroll
        for (int kk = 0; kk < 2; ++kk) {
            const int kg = kk * 4 + lk;
            bf16x8 a[4], b[4][2];
#pragma unroll
            for (int m = 0; m < 4; ++m) {
                int row  = wm * 64 + m * 16 + ln;
                int ccol = (kg ^ (row & 7)) * 8;
                a[m] = *(const bf16x8*)(Ab + row * 64 + ccol);
            }
#pragma unroll
            for (int g = 0; g < 4; ++g)
#pragma unroll
                for (int h = 0; h < 2; ++h) {
                    int n    = wn * 128 + g * 32 + h * 16 + ln;
                    int ccol = (kg ^ (n & 7)) * 8;
                    b[g][h] = *(const bf16x8*)(Bb + n * 64 + ccol);
                }
#pragma unroll
            for (int m = 0; m < 4; ++m)
#pragma unroll
                for (int g = 0; g < 4; ++g)
#pragma unroll
                    for (int h = 0; h < 2; ++h)
                        acc[m][g][h] = __builtin_amdgcn_mfma_f32_16x16x32_bf16(a[m], b[g][h], acc[m][g][h], 0, 0, 0);
        }
    }

    // ---- peeled kt=16: compute only (buffer 0) ----
    {
        __syncthreads();
        const __bf16* Ab = As;   // 16 & 1 == 0
        const __bf16* Bb = Bs;
#pragma unroll
        for (int kk = 0; kk < 2; ++kk) {
            const int kg = kk * 4 + lk;
            bf16x8 a[4], b[4][2];
#pragma unroll
            for (int m = 0; m < 4; ++m) {
                int row  = wm * 64 + m * 16 + ln;
                int ccol = (kg ^ (row & 7)) * 8;
                a[m] = *(const bf16x8*)(Ab + row * 64 + ccol);
            }
#pragma unroll
            for (int g = 0; g < 4; ++g)
#pragma unroll
                for (int h = 0; h < 2; ++h) {
                    int n    = wn * 128 + g * 32 + h * 16 + ln;
                    int ccol = (kg ^ (n & 7)) * 8;
                    b[g][h] = *(const bf16x8*)(Bb + n * 64 + ccol);
                }
#pragma unroll
            for (int m = 0; m < 4; ++m)
#pragma unroll
                for (int g = 0; g < 4; ++g)
#pragma unroll
                    for (int h = 0; h < 2; ++h)
                        acc[m][g][h] = __builtin_amdgcn_mfma_f32_16x16x32_bf16(a[m], b[g][h], acc[m][g][h], 0, 0, 0);
        }
    }

    // ---- fused LSTM epilogue: lane owns unit u per h-half, all 4 gates ----
    const int ublk = yb * 2 + wn;
#pragma unroll
    for (int h = 0; h < 2; ++h) {
        const int u  = ublk * 32 + h * 16 + ln;
        const float bi  = bias[u];
        const float bfv = bias[UNITS + u];
        const float bg  = bias[2 * UNITS + u];
        const float bo  = bias[3 * UNITS + u];
#pragma unroll
        for (int m = 0; m < 4; ++m) {
            const int row0 = rb * 256 + wm * 64 + m * 16 + lk * 4;
#pragma unroll
            for (int r = 0; r < 4; ++r) {
                const size_t idx = ((size_t)(row0 + r) << 10) + u;
                float ig = sigmoid_f(acc[m][0][h][r] + bi);
                float fg = sigmoid_f(acc[m][1][h][r] + bfv);
                float gg = tanh_f(acc[m][2][h][r] + bg);
                float og = sigmoid_f(acc[m][3][h][r] + bo);
                float cn = fg * cstate[idx] + ig * gg;
                cstate[idx] = cn;
                hout[idx] = (__bf16)(og * tanh_f(cn));
            }
        }
    }
}

// ---------------- final dense: [4096,1024] @ [1024,640] -> logits fp32 ----------------
__global__ void __launch_bounds__(256) dense_kernel(
    const __bf16* __restrict__ hin,
    const __bf16* __restrict__ Wt2p,
    float*        __restrict__ logits)
{
    __shared__ __bf16 As[128 * 64];
    __shared__ __bf16 Bs[128 * 64];

    const int tid  = threadIdx.x;
    const int wid  = tid >> 6;
    const int lane = tid & 63;
    const int ln   = lane & 15;
    const int lk   = lane >> 4;
    const int wm   = wid >> 1;
    const int wn   = wid & 1;
    const int rb   = blockIdx.x;
    const int nb   = blockIdx.y;

    floatx4 acc[4][4];
#pragma unroll
    for (int m = 0; m < 4; ++m)
#pragma unroll
        for (int g = 0; g < 4; ++g)
            acc[m][g] = (floatx4){0.f, 0.f, 0.f, 0.f};

    int s_row[4], s_kgd[4];
#pragma unroll
    for (int q = 0; q < 4; ++q) {
        int flat = q * 256 + tid;
        int row  = flat >> 3;
        s_row[q] = row;
        s_kgd[q] = (flat & 7) ^ (row & 7);
    }

    for (int kt = 0; kt < 16; ++kt) {
        __syncthreads();
#pragma unroll
        for (int q = 0; q < 4; ++q) {
            const int row = s_row[q], kgd = s_kgd[q];
            const __bf16* gp = hin + ((size_t)(rb * 128 + row) << 10) + kt * 64 + kgd * 8;
            __builtin_amdgcn_global_load_lds((gas_char*)gp,
                (las_char*)(As + (size_t)(q * 256 + (wid << 6)) * 8), 16, 0, 0);
        }
#pragma unroll
        for (int q = 0; q < 4; ++q) {
            const int n = s_row[q], kgd = s_kgd[q];
            const __bf16* gp = Wt2p + ((size_t)(nb * 128 + n) << 10) + kt * 64 + kgd * 8;
            __builtin_amdgcn_global_load_lds((gas_char*)gp,
                (las_char*)(Bs + (size_t)(q * 256 + (wid << 6)) * 8), 16, 0, 0);
        }
        __syncthreads();
#pragma unroll
        for (int kk = 0; kk < 2; ++kk) {
            const int kg = kk * 4 + lk;
            bf16x8 a[4], b[4];
#pragma unroll
            for (int m = 0; m < 4; ++m) {
                int row  = wm * 64 + m * 16 + ln;
                int ccol = (kg ^ (row & 7)) * 8;
                a[m] = *(const bf16x8*)(As + row * 64 + ccol);
            }
#pragma unroll
            for (int g = 0; g < 4; ++g) {
                int n    = g * 32 + wn * 16 + ln;
                int ccol = (kg ^ (n & 7)) * 8;
                b[g] = *(const bf16x8*)(Bs + n * 64 + ccol);
            }
#pragma unroll
            for (int m = 0; m < 4; ++m)
#pragma unroll
                for (int g = 0; g < 4; ++g)
                    acc[m][g] = __builtin_amdgcn_mfma_f32_16x16x32_bf16(a[m], b[g], acc[m][g], 0, 0, 0);
        }
    }

#pragma unroll
    for (int m = 0; m < 4; ++m) {
        const int row0 = rb * 128 + wm * 64 + m * 16 + lk * 4;
#pragma unroll
        for (int g = 0; g < 4; ++g) {
            const int n = nb * 128 + g * 32 + wn * 16 + ln;
#pragma unroll
            for (int r = 0; r < 4; ++r)
                logits[(size_t)(row0 + r) * NPAD + n] = acc[m][g][r];
        }
    }
}

// ---------------- row softmax over 578 cols (+b2) ----------------
__global__ void __launch_bounds__(256) softmax_kernel(
    const float* __restrict__ logits,
    const float* __restrict__ b2,
    float* __restrict__ out)
{
    const int row = blockIdx.x;
    const int tid = threadIdx.x;
    __shared__ float red[8];

    float z[3];
    float lmax = -1e30f;
#pragma unroll
    for (int j = 0; j < 3; ++j) {
        int col = tid + j * 256;
        if (col < VOCAB) {
            z[j] = logits[(size_t)row * NPAD + col] + b2[col];
            lmax = fmaxf(lmax, z[j]);
        } else z[j] = -1e30f;
    }
    for (int off = 32; off > 0; off >>= 1) lmax = fmaxf(lmax, __shfl_xor(lmax, off));
    if ((tid & 63) == 0) red[tid >> 6] = lmax;
    __syncthreads();
    lmax = fmaxf(fmaxf(red[0], red[1]), fmaxf(red[2], red[3]));
    __syncthreads();

    float lsum = 0.f;
#pragma unroll
    for (int j = 0; j < 3; ++j) {
        int col = tid + j * 256;
        if (col < VOCAB) { z[j] = __expf(z[j] - lmax); lsum += z[j]; }
    }
    for (int off = 32; off > 0; off >>= 1) lsum += __shfl_xor(lsum, off);
    if ((tid & 63) == 0) red[tid >> 6] = lsum;
    __syncthreads();
    lsum = red[0] + red[1] + red[2] + red[3];
    float inv = 1.f / lsum;
#pragma unroll
    for (int j = 0; j < 3; ++j) {
        int col = tid + j * 256;
        if (col < VOCAB) out[(size_t)row * VOCAB + col] = z[j] * inv;
    }
}

// ---------------- launch ----------------
extern "C" void kernel_launch(void* const* d_in, const int* in_sizes, int n_in,
                              void* d_out, int out_size, void* d_ws, size_t ws_size,
                              hipStream_t stream)
{
    const float* x    = (const float*)d_in[0];
    const float* kern = (const float*)d_in[1];
    const float* reck = (const float*)d_in[2];
    const float* bias = (const float*)d_in[3];
    const float* w2   = (const float*)d_in[4];
    const float* b2   = (const float*)d_in[5];
    float* out = (float*)d_out;

    char* ws = (char*)d_ws;
    size_t off = 0;
    auto alloc = [&](size_t bytes) {
        char* p = ws + off;
        off += (bytes + 255) & ~(size_t)255;
        return p;
    };
    __bf16* Wtp    = (__bf16*)alloc((size_t)4096 * KLSTM * 2);
    __bf16* Wt2p   = (__bf16*)alloc((size_t)NPAD * 1024 * 2);
    __bf16* xbf    = (__bf16*)alloc((size_t)BATCH * SEQ * FEAT * 2);
    __bf16* h0     = (__bf16*)alloc((size_t)BATCH * UNITS * 2);
    __bf16* h1     = (__bf16*)alloc((size_t)BATCH * UNITS * 2);
    float*  cst    = (float*)alloc((size_t)BATCH * UNITS * 4);
    float*  logits = (float*)alloc((size_t)BATCH * NPAD * 4);
    if (off > ws_size) return;  // loud failure: output stays zero

    // allow 128 KB dynamic LDS (idempotent; graph-capture safe)
    (void)hipFuncSetAttribute((const void*)lstm_step_kernel,
                              hipFuncAttributeMaxDynamicSharedMemorySize, 128 * 1024);

    (void)hipMemsetAsync(h0, 0, (size_t)BATCH * UNITS * 2, stream);
    (void)hipMemsetAsync(cst, 0, (size_t)BATCH * UNITS * 4, stream);

    convert_x_kernel<<<(BATCH * SEQ * FEAT / 4 + 255) / 256, 256, 0, stream>>>(x, xbf);
    convert_weights_kernel<<<(4096 * KLSTM + 255) / 256, 256, 0, stream>>>(kern, reck, Wtp);
    convert_w2_kernel<<<(NPAD * 1024 + 255) / 256, 256, 0, stream>>>(w2, Wt2p);

    __bf16* hin = h0; __bf16* hout = h1;
    for (int t = 0; t < SEQ; ++t) {
        lstm_step_kernel<<<256, 512, 128 * 1024, stream>>>(xbf, Wtp, bias, hin, hout, cst, t);
        __bf16* tmp = hin; hin = hout; hout = tmp;
    }

    dense_kernel<<<dim3(32, 5), 256, 0, stream>>>(hin, Wt2p, logits);
    softmax_kernel<<<BATCH, 256, 0, stream>>>(logits, b2, out);
}